// Round 1
// baseline (323.117 us; speedup 1.0000x reference)
//
#include <hip/hip_runtime.h>
#include <hip/hip_bf16.h>

// LoRA linear: out[m,o] = bias[o] + 2 * sum_r (sum_i x[m,i]*A[r,i]) * B[o,r]
// x: [8192, 4096] f32, A: [16, 4096] f32, B: [4096, 16] f32, bias: [4096] f32
// t (intermediate [8192,16] f32) lives in d_ws (512 KB).

constexpr int IN_F  = 4096;
constexpr int OUT_F = 4096;
constexpr int RANK  = 16;
constexpr int M_TOT = 4 * 2048;           // 8192 token rows
constexpr float SCALING = 2.0f;           // ALPHA / R

// ---------------- Kernel 1: t = 2 * (x @ A^T) ----------------
// block = 256 threads (4 waves). Each wave handles 4 rows => 16 rows/block.
// grid = 8192 / 16 = 512 blocks.
// Lane covers float4 column chunks c4 = lane + 64*j, j = 0..15 (coalesced
// 1 KiB per wave-instr for both x and A). All 4 waves stream the same A
// chunks -> L1 sharing amortizes the 256 KB A re-read.
__global__ __launch_bounds__(256) void lora_phase1(
    const float* __restrict__ x, const float* __restrict__ A,
    float* __restrict__ t)
{
    const int lane = threadIdx.x & 63;
    const int wave = threadIdx.x >> 6;
    const int row0 = blockIdx.x * 16 + wave * 4;   // 4 rows for this wave

    float acc[4][RANK];
#pragma unroll
    for (int p = 0; p < 4; ++p)
#pragma unroll
        for (int r = 0; r < RANK; ++r) acc[p][r] = 0.0f;

    const float4* __restrict__ A4 = (const float4*)A;

    for (int j = 0; j < 16; ++j) {
        const int c4 = lane + 64 * j;              // float4 index in row

        float4 av[RANK];
#pragma unroll
        for (int r = 0; r < RANK; ++r)
            av[r] = A4[r * (IN_F / 4) + c4];

#pragma unroll
        for (int p = 0; p < 4; ++p) {
            const float4 xv =
                *(const float4*)(x + (size_t)(row0 + p) * IN_F + 4 * c4);
#pragma unroll
            for (int r = 0; r < RANK; ++r) {
                acc[p][r] += xv.x * av[r].x;
                acc[p][r] += xv.y * av[r].y;
                acc[p][r] += xv.z * av[r].z;
                acc[p][r] += xv.w * av[r].w;
            }
        }
    }

    // Cross-lane butterfly reduce (64 lanes) for each of the 4x16 sums.
#pragma unroll
    for (int p = 0; p < 4; ++p) {
#pragma unroll
        for (int r = 0; r < RANK; ++r) {
            float v = acc[p][r];
#pragma unroll
            for (int s = 1; s < 64; s <<= 1)
                v += __shfl_xor(v, s, 64);
            acc[p][r] = v;
        }
        // lane k (k < 16) writes t[row0+p][k]; select acc[p][lane] via cndmask chain
        float out_v = 0.0f;
#pragma unroll
        for (int r = 0; r < RANK; ++r)
            out_v = (lane == r) ? acc[p][r] : out_v;
        if (lane < RANK)
            t[(size_t)(row0 + p) * RANK + lane] = SCALING * out_v;
    }
}

// ---------------- Kernel 2: out = t @ B^T + bias ----------------
// block = 256 threads; thread owns 4 consecutive o-columns -> block covers
// 1024 columns. grid = (4 col-blocks, 256 row-tiles); 32 rows per block.
// B fragment (4 cols x 16 ranks = 64 floats) held in registers for all rows.
// t[m][0:16] is uniform across the block -> scalar loads.
__global__ __launch_bounds__(256) void lora_phase2(
    const float* __restrict__ t, const float* __restrict__ B,
    const float* __restrict__ bias, float* __restrict__ out)
{
    const int o0 = blockIdx.x * 1024 + threadIdx.x * 4;  // first owned column
    const int m0 = blockIdx.y * 32;                      // first row

    // b[q][rr] = B[o0+q][4*rr .. 4*rr+3]   (B row-major [OUT_F][16])
    const float4* __restrict__ B4 = (const float4*)B;
    float4 b[4][4];
#pragma unroll
    for (int q = 0; q < 4; ++q)
#pragma unroll
        for (int rr = 0; rr < 4; ++rr)
            b[q][rr] = B4[(size_t)(o0 + q) * 4 + rr];

    const float4 bs = *(const float4*)(bias + o0);
    const float4* __restrict__ t4 = (const float4*)t;

    for (int mi = 0; mi < 32; ++mi) {
        const int m = m0 + mi;
        float4 tv[4];
#pragma unroll
        for (int rr = 0; rr < 4; ++rr)
            tv[rr] = t4[(size_t)m * 4 + rr];   // uniform -> s_load

        float v[4] = {bs.x, bs.y, bs.z, bs.w};
#pragma unroll
        for (int q = 0; q < 4; ++q) {
#pragma unroll
            for (int rr = 0; rr < 4; ++rr) {
                v[q] += b[q][rr].x * tv[rr].x;
                v[q] += b[q][rr].y * tv[rr].y;
                v[q] += b[q][rr].z * tv[rr].z;
                v[q] += b[q][rr].w * tv[rr].w;
            }
        }
        float4 o4 = {v[0], v[1], v[2], v[3]};
        *(float4*)(out + (size_t)m * OUT_F + o0) = o4;
    }
}

extern "C" void kernel_launch(void* const* d_in, const int* in_sizes, int n_in,
                              void* d_out, int out_size, void* d_ws, size_t ws_size,
                              hipStream_t stream) {
    const float* x    = (const float*)d_in[0];  // [8192, 4096]
    const float* A    = (const float*)d_in[1];  // [16, 4096]
    const float* B    = (const float*)d_in[2];  // [4096, 16]
    const float* bias = (const float*)d_in[3];  // [4096]
    float* out = (float*)d_out;                 // [8192, 4096]
    float* t   = (float*)d_ws;                  // [8192, 16] scratch (512 KB)

    // Phase 1: t = 2 * x @ A^T
    lora_phase1<<<dim3(M_TOT / 16), dim3(256), 0, stream>>>(x, A, t);
    // Phase 2: out = t @ B^T + bias
    lora_phase2<<<dim3(OUT_F / 1024, M_TOT / 32), dim3(256), 0, stream>>>(t, B, bias, out);
}

// Round 2
// 320.277 us; speedup vs baseline: 1.0089x; 1.0089x over previous
//
#include <hip/hip_runtime.h>
#include <hip/hip_bf16.h>

// LoRA linear: out[m,o] = bias[o] + 2 * sum_r (sum_i x[m,i]*A[r,i]) * B[o,r]
// x: [8192, 4096] f32, A: [16, 4096] f32, B: [4096, 16] f32, bias: [4096] f32
// t (intermediate [8192,16] f32) lives in d_ws (512 KB).

constexpr int IN_F  = 4096;
constexpr int OUT_F = 4096;
constexpr int RANK  = 16;
constexpr int M_TOT = 4 * 2048;           // 8192 token rows
constexpr float SCALING = 2.0f;           // ALPHA / R

// ---------------- Kernel 1: t = 2 * (x @ A^T) ----------------
// block = 256 (4 waves); wave handles 2 rows -> 8 rows/block.
// grid = 8192/8 = 1024 blocks = 4 blocks/CU = 16 waves/CU.
// acc = 2x16 = 32 VGPRs; 18 float4 loads per j-iteration fit in flight
// under the 128-VGPR budget (__launch_bounds__(256,4)) -> single vmcnt
// wait per iteration, hidden across 4 waves/SIMD.
__global__ __launch_bounds__(256, 4) void lora_phase1(
    const float* __restrict__ x, const float* __restrict__ A,
    float* __restrict__ t)
{
    const int lane = threadIdx.x & 63;
    const int wave = threadIdx.x >> 6;
    const int row0 = blockIdx.x * 8 + wave * 2;    // 2 rows for this wave

    float acc0[RANK], acc1[RANK];
#pragma unroll
    for (int r = 0; r < RANK; ++r) { acc0[r] = 0.0f; acc1[r] = 0.0f; }

    const float4* __restrict__ A4 = (const float4*)A;
    const float4* __restrict__ x0 = (const float4*)(x + (size_t)row0 * IN_F);
    const float4* __restrict__ x1 = (const float4*)(x + (size_t)(row0 + 1) * IN_F);

#pragma unroll 1
    for (int j = 0; j < 16; ++j) {
        const int c4 = lane + 64 * j;              // float4 index in row

        const float4 xv0 = x0[c4];
        const float4 xv1 = x1[c4];
        float4 av[RANK];
#pragma unroll
        for (int r = 0; r < RANK; ++r)
            av[r] = A4[r * (IN_F / 4) + c4];

#pragma unroll
        for (int r = 0; r < RANK; ++r) {
            acc0[r] += xv0.x * av[r].x;
            acc0[r] += xv0.y * av[r].y;
            acc0[r] += xv0.z * av[r].z;
            acc0[r] += xv0.w * av[r].w;
            acc1[r] += xv1.x * av[r].x;
            acc1[r] += xv1.y * av[r].y;
            acc1[r] += xv1.z * av[r].z;
            acc1[r] += xv1.w * av[r].w;
        }
    }

    // Cross-lane butterfly reduce (64 lanes) for each of the 2x16 sums.
#pragma unroll
    for (int p = 0; p < 2; ++p) {
        float out_v = 0.0f;
#pragma unroll
        for (int r = 0; r < RANK; ++r) {
            float v = (p == 0) ? acc0[r] : acc1[r];
#pragma unroll
            for (int s = 1; s < 64; s <<= 1)
                v += __shfl_xor(v, s, 64);
            out_v = (lane == r) ? v : out_v;
        }
        if (lane < RANK)
            t[(size_t)(row0 + p) * RANK + lane] = SCALING * out_v;
    }
}

// ---------------- Kernel 2: out = t @ B^T + bias ----------------
// block = 256; thread owns 4 cols x 4 rows. grid (4, 2048) = 8192 blocks
// -> deep per-CU block queue. All 32 float4 loads issued before one wait,
// then 16x4 FMAs and 4 coalesced float4 stores.
__global__ __launch_bounds__(256) void lora_phase2(
    const float* __restrict__ t, const float* __restrict__ B,
    const float* __restrict__ bias, float* __restrict__ out)
{
    const int o0 = blockIdx.x * 1024 + threadIdx.x * 4;  // first owned column
    const int m0 = blockIdx.y * 4;                       // first row

    const float4* __restrict__ B4 = (const float4*)B;
    const float4* __restrict__ t4 = (const float4*)t;

    // b[q][rr] = B[o0+q][4*rr .. 4*rr+3]
    float4 b[4][4];
#pragma unroll
    for (int q = 0; q < 4; ++q)
#pragma unroll
        for (int rr = 0; rr < 4; ++rr)
            b[q][rr] = B4[(size_t)(o0 + q) * 4 + rr];

    // t rows for this tile (uniform across block -> scalar loads)
    float4 tv[4][4];
#pragma unroll
    for (int mi = 0; mi < 4; ++mi)
#pragma unroll
        for (int rr = 0; rr < 4; ++rr)
            tv[mi][rr] = t4[(size_t)(m0 + mi) * 4 + rr];

    const float4 bs = *(const float4*)(bias + o0);

#pragma unroll
    for (int mi = 0; mi < 4; ++mi) {
        float v[4] = {bs.x, bs.y, bs.z, bs.w};
#pragma unroll
        for (int q = 0; q < 4; ++q) {
#pragma unroll
            for (int rr = 0; rr < 4; ++rr) {
                v[q] += b[q][rr].x * tv[mi][rr].x;
                v[q] += b[q][rr].y * tv[mi][rr].y;
                v[q] += b[q][rr].z * tv[mi][rr].z;
                v[q] += b[q][rr].w * tv[mi][rr].w;
            }
        }
        float4 o4 = {v[0], v[1], v[2], v[3]};
        *(float4*)(out + (size_t)(m0 + mi) * OUT_F + o0) = o4;
    }
}

extern "C" void kernel_launch(void* const* d_in, const int* in_sizes, int n_in,
                              void* d_out, int out_size, void* d_ws, size_t ws_size,
                              hipStream_t stream) {
    const float* x    = (const float*)d_in[0];  // [8192, 4096]
    const float* A    = (const float*)d_in[1];  // [16, 4096]
    const float* B    = (const float*)d_in[2];  // [4096, 16]
    const float* bias = (const float*)d_in[3];  // [4096]
    float* out = (float*)d_out;                 // [8192, 4096]
    float* t   = (float*)d_ws;                  // [8192, 16] scratch (512 KB)

    // Phase 1: t = 2 * x @ A^T
    lora_phase1<<<dim3(M_TOT / 8), dim3(256), 0, stream>>>(x, A, t);
    // Phase 2: out = t @ B^T + bias
    lora_phase2<<<dim3(OUT_F / 1024, M_TOT / 4), dim3(256), 0, stream>>>(t, B, bias, out);
}

// Round 3
// 295.919 us; speedup vs baseline: 1.0919x; 1.0823x over previous
//
#include <hip/hip_runtime.h>
#include <hip/hip_bf16.h>
#include <stdint.h>

// LoRA linear: out[m,o] = bias[o] + 2 * sum_r (sum_i x[m,i]*A[r,i]) * B[o,r]
// x: [8192, 4096] f32, A: [16, 4096] f32, B: [4096, 16] f32, bias: [4096] f32
// t (intermediate [8192,16] f32) lives in d_ws (512 KB).

constexpr int IN_F  = 4096;
constexpr int OUT_F = 4096;
constexpr int RANK  = 16;
constexpr int M_TOT = 4 * 2048;           // 8192 token rows
constexpr float SCALING = 2.0f;           // ALPHA / R

typedef const __attribute__((address_space(1))) void* as1_cvp;
typedef __attribute__((address_space(3))) void*       as3_vp;

// ---------------- Kernel 1: t = 2 * (x @ A^T) ----------------
// block = 256 (4 waves); wave handles 2 rows -> 8 rows/block; grid 1024.
// A j-chunk (16 ranks x 256 floats = 16 KB) staged into LDS, double-buffered
// (32 KB total), via global_load_lds width=16: wave w stages ranks 4w..4w+3,
// lane data lands at base + lane*16 == As[buf][r][lane] -- exactly the
// consume layout. x stays on the vmcnt path, prefetched one j ahead.
// One __syncthreads per j: its vmcnt(0)+lgkmcnt(0) drain covers both the
// j+1 staging and the j+1 x prefetch issued just above it.
__global__ __launch_bounds__(256, 4) void lora_phase1(
    const float* __restrict__ x, const float* __restrict__ A,
    float* __restrict__ t)
{
    __shared__ float4 As[2][RANK][64];    // 2 x 16 KB
    const int lane = threadIdx.x & 63;
    const int wave = threadIdx.x >> 6;
    const int row0 = blockIdx.x * 8 + wave * 2;

    const float4* __restrict__ A4 = (const float4*)A;
    const float4* __restrict__ x0 = (const float4*)(x + (size_t)row0 * IN_F);
    const float4* __restrict__ x1 = (const float4*)(x + (size_t)(row0 + 1) * IN_F);

    float acc0[RANK], acc1[RANK];
#pragma unroll
    for (int r = 0; r < RANK; ++r) { acc0[r] = 0.0f; acc1[r] = 0.0f; }

    // Stage j=0 into buf 0; prefetch x chunk 0.
#pragma unroll
    for (int rr = 0; rr < 4; ++rr) {
        const int r = wave * 4 + rr;
        __builtin_amdgcn_global_load_lds((as1_cvp)(A4 + (size_t)r * (IN_F / 4) + lane),
                                         (as3_vp)(&As[0][r][0]), 16, 0, 0);
    }
    float4 xc0 = x0[lane];
    float4 xc1 = x1[lane];
    __syncthreads();

    int buf = 0;
#pragma unroll 1
    for (int j = 0; j < 16; ++j) {
        float4 xn0, xn1;
        if (j < 15) {
            const int c4 = (j + 1) * 64 + lane;
#pragma unroll
            for (int rr = 0; rr < 4; ++rr) {
                const int r = wave * 4 + rr;
                __builtin_amdgcn_global_load_lds(
                    (as1_cvp)(A4 + (size_t)r * (IN_F / 4) + c4),
                    (as3_vp)(&As[buf ^ 1][r][0]), 16, 0, 0);
            }
            xn0 = x0[c4];
            xn1 = x1[c4];
        }

#pragma unroll
        for (int r = 0; r < RANK; ++r) {
            const float4 av = As[buf][r][lane];   // ds_read_b128
            acc0[r] += xc0.x * av.x;
            acc0[r] += xc0.y * av.y;
            acc0[r] += xc0.z * av.z;
            acc0[r] += xc0.w * av.w;
            acc1[r] += xc1.x * av.x;
            acc1[r] += xc1.y * av.y;
            acc1[r] += xc1.z * av.z;
            acc1[r] += xc1.w * av.w;
        }

        if (j < 15) {
            __syncthreads();   // all waves done reading As[buf]; staging drained
            buf ^= 1;
            xc0 = xn0;
            xc1 = xn1;
        }
    }

    // Cross-lane butterfly reduce (64 lanes) for each of the 2x16 sums.
#pragma unroll
    for (int p = 0; p < 2; ++p) {
        float out_v = 0.0f;
#pragma unroll
        for (int r = 0; r < RANK; ++r) {
            float v = (p == 0) ? acc0[r] : acc1[r];
#pragma unroll
            for (int s = 1; s < 64; s <<= 1)
                v += __shfl_xor(v, s, 64);
            out_v = (lane == r) ? v : out_v;
        }
        if (lane < RANK)
            t[(size_t)(row0 + p) * RANK + lane] = SCALING * out_v;
    }
}

// ---------------- Kernel 2: out = t @ B^T + bias ----------------
// block = 256; thread owns 4 cols x 4 rows. grid (4, 2048) = 8192 blocks.
// All 32 float4 loads issued before one wait, then 64 FMAs and 4 coalesced
// float4 stores. Store-throughput bound.
__global__ __launch_bounds__(256) void lora_phase2(
    const float* __restrict__ t, const float* __restrict__ B,
    const float* __restrict__ bias, float* __restrict__ out)
{
    const int o0 = blockIdx.x * 1024 + threadIdx.x * 4;  // first owned column
    const int m0 = blockIdx.y * 4;                       // first row

    const float4* __restrict__ B4 = (const float4*)B;
    const float4* __restrict__ t4 = (const float4*)t;

    // b[q][rr] = B[o0+q][4*rr .. 4*rr+3]
    float4 b[4][4];
#pragma unroll
    for (int q = 0; q < 4; ++q)
#pragma unroll
        for (int rr = 0; rr < 4; ++rr)
            b[q][rr] = B4[(size_t)(o0 + q) * 4 + rr];

    // t rows for this tile (uniform across block -> scalar loads)
    float4 tv[4][4];
#pragma unroll
    for (int mi = 0; mi < 4; ++mi)
#pragma unroll
        for (int rr = 0; rr < 4; ++rr)
            tv[mi][rr] = t4[(size_t)(m0 + mi) * 4 + rr];

    const float4 bs = *(const float4*)(bias + o0);

#pragma unroll
    for (int mi = 0; mi < 4; ++mi) {
        float v[4] = {bs.x, bs.y, bs.z, bs.w};
#pragma unroll
        for (int q = 0; q < 4; ++q) {
#pragma unroll
            for (int rr = 0; rr < 4; ++rr) {
                v[q] += b[q][rr].x * tv[mi][rr].x;
                v[q] += b[q][rr].y * tv[mi][rr].y;
                v[q] += b[q][rr].z * tv[mi][rr].z;
                v[q] += b[q][rr].w * tv[mi][rr].w;
            }
        }
        float4 o4 = {v[0], v[1], v[2], v[3]};
        *(float4*)(out + (size_t)(m0 + mi) * OUT_F + o0) = o4;
    }
}

extern "C" void kernel_launch(void* const* d_in, const int* in_sizes, int n_in,
                              void* d_out, int out_size, void* d_ws, size_t ws_size,
                              hipStream_t stream) {
    const float* x    = (const float*)d_in[0];  // [8192, 4096]
    const float* A    = (const float*)d_in[1];  // [16, 4096]
    const float* B    = (const float*)d_in[2];  // [4096, 16]
    const float* bias = (const float*)d_in[3];  // [4096]
    float* out = (float*)d_out;                 // [8192, 4096]
    float* t   = (float*)d_ws;                  // [8192, 16] scratch (512 KB)

    // Phase 1: t = 2 * x @ A^T
    lora_phase1<<<dim3(M_TOT / 8), dim3(256), 0, stream>>>(x, A, t);
    // Phase 2: out = t @ B^T + bias
    lora_phase2<<<dim3(OUT_F / 1024, M_TOT / 4), dim3(256), 0, stream>>>(t, B, bias, out);
}